// Round 8
// baseline (207.327 us; speedup 1.0000x reference)
//
#include <hip/hip_runtime.h>
#include <hip/hip_bf16.h>
#include <stdint.h>

#define NSEQ 4096
#define DDIM 512
#define NB   8

#define BMN 256
#define BK  64
#define NT  (NSEQ / BK)   // 64 K-tiles

typedef float f32x16 __attribute__((ext_vector_type(16)));
typedef __bf16 bf16x8 __attribute__((ext_vector_type(8)));

typedef const void __attribute__((address_space(1))) gvoid_t;
typedef void __attribute__((address_space(3))) svoid_t;

#define SBAR() do { __builtin_amdgcn_s_barrier(); asm volatile("" ::: "memory"); } while (0)

__device__ __forceinline__ unsigned short f2bf(float f) {
    union { float f; unsigned int u; } v;
    v.f = f;
    unsigned int u = v.u;
    u += 0x7FFFu + ((u >> 16) & 1u);   // RNE
    return (unsigned short)(u >> 16);
}

// ---------------------------------------------------------------------------
// Fused prep: blocks [0,8192) build T; blocks [8192,12288) transpose x -> xT.
// T[i][j] = bf16(exp(clamp(w(i-j)))); xT[b][d][j] = bf16(x[b][j][d]).
// ---------------------------------------------------------------------------
__global__ void fused_prep(const float* __restrict__ x,
                           const float* __restrict__ pos,
                           const float* __restrict__ zero,
                           const float* __restrict__ neg,
                           unsigned short* __restrict__ T,
                           unsigned short* __restrict__ xT) {
    __shared__ unsigned short tl[64][72];
    if (blockIdx.x < 8192) {
        int tid = blockIdx.x * 256 + threadIdx.x;
        int i  = tid >> 9;
        int j0 = (tid & 511) << 3;
        float z = zero[0];
        unsigned short r[8];
#pragma unroll
        for (int e = 0; e < 8; ++e) {
            int j = j0 + e;
            int d = i - j;
            float v;
            if (d > 0)       v = pos[d - 1];
            else if (d == 0) v = z;
            else             v = neg[NSEQ - 1 + d];
            v = fminf(fmaxf(v, -60.0f), 30.0f);
            r[e] = f2bf(__expf(v));
        }
        uint4 o;
        o.x = (unsigned int)r[0] | ((unsigned int)r[1] << 16);
        o.y = (unsigned int)r[2] | ((unsigned int)r[3] << 16);
        o.z = (unsigned int)r[4] | ((unsigned int)r[5] << 16);
        o.w = (unsigned int)r[6] | ((unsigned int)r[7] << 16);
        *(uint4*)(T + (size_t)i * NSEQ + j0) = o;
    } else {
        int t   = blockIdx.x - 8192;        // 0..4095
        int b   = t >> 9;
        int rem = t & 511;
        int j0  = (rem >> 3) << 6;
        int d0  = (rem & 7) << 6;
        const float* xb = x + (size_t)b * NSEQ * DDIM;
#pragma unroll
        for (int e = 0; e < 4; ++e) {
            int idx = e * 256 + threadIdx.x;    // 0..1023
            int r   = idx >> 4;                 // j offset 0..63
            int c4  = (idx & 15) << 2;          // d offset (x4)
            float4 v = *(const float4*)&xb[(size_t)(j0 + r) * DDIM + d0 + c4];
            ushort4 o;
            o.x = f2bf(v.x); o.y = f2bf(v.y); o.z = f2bf(v.z); o.w = f2bf(v.w);
            *(ushort4*)&tl[r][c4] = o;
        }
        __syncthreads();
        unsigned short* xtb = xT + (size_t)b * DDIM * NSEQ;
#pragma unroll
        for (int e = 0; e < 4; ++e) {
            int idx = e * 256 + threadIdx.x;
            int d   = idx >> 4;                 // d offset 0..63
            int jq  = (idx & 15) << 2;          // j offset (x4)
            ushort4 o;
            o.x = tl[jq + 0][d]; o.y = tl[jq + 1][d];
            o.z = tl[jq + 2][d]; o.w = tl[jq + 3][d];
            *(ushort4*)&xtb[(size_t)(d0 + d) * NSEQ + j0 + jq] = o;
        }
    }
}

// ---------------------------------------------------------------------------
// GEMM: out[b] = T @ x[b].  32x32x16 MFMA, Toeplitz A-register-ring refreshed
// from GLOBAL T (no sA, no cross-wave A dependency).  sB: 4 buffers (128 KB)
// -> stage(kt+2) never collides with live reads; sync = ONE vmcnt(0) + ONE
// barrier per tile, everything else free-runs.  8 waves (2M x 4N), n-half
// split B-reads pipelined across the tile boundary.
// ---------------------------------------------------------------------------
__global__ __launch_bounds__(512, 2) void gemm_toep32g(
        const unsigned short* __restrict__ T,    // [NSEQ][NSEQ] bf16
        const unsigned short* __restrict__ xT,   // [NB][DDIM][NSEQ] bf16
        float* __restrict__ out) {               // [NB][NSEQ][DDIM] f32
    __shared__ __attribute__((aligned(16))) unsigned short sB[4][BMN * BK];  // 32 KB x4

    const int tid  = threadIdx.x;
    const int lane = tid & 63;
    const int wid  = tid >> 6;      // 0..7
    const int wm   = wid >> 2;      // 0..1 -> 128-row half
    const int wn   = wid & 3;       // 0..3 -> 64-col quarter
    const int l31  = lane & 31;
    const int lhi2 = lane >> 5;     // 0..1

    // ---- XCD-aware bijective block swizzle (256 blocks, 8 XCDs) ----
    int lin = blockIdx.x;
    int swz = (lin & 7) * 32 + (lin >> 3);
    int it  = swz >> 4;
    int tn  = (swz & 15) & 1;
    int b   = (swz & 15) >> 1;
    const int i0 = it * BMN;
    const int n0 = tn * BMN;

    const unsigned short* Bg = xT + ((size_t)b * DDIM + n0) * NSEQ;

    // staging geometry: 8 rows x 128B per instr, pre-swizzled source chunk
    const int srow = lane >> 3;
    const int schk = (lane & 7) ^ srow;
    uint32_t offB[4];
#pragma unroll
    for (int q = 0; q < 4; ++q)
        offB[q] = (uint32_t)((q * 8 + wid) * 8 + srow) * NSEQ + schk * 8;

#define STAGE(BUF, K0) do { \
    _Pragma("unroll") \
    for (int q_ = 0; q_ < 4; ++q_) \
        __builtin_amdgcn_global_load_lds( \
            (gvoid_t*)(const void*)(Bg + offB[q_] + (K0)), \
            (svoid_t*)(void*)(&sB[BUF][0] + (q_ * 8 + wid) * 512), 16, 0, 0); \
} while (0)

    f32x16 acc[4][2];
#pragma unroll
    for (int m = 0; m < 4; ++m)
#pragma unroll
        for (int n = 0; n < 2; ++n)
#pragma unroll
            for (int r = 0; r < 16; ++r)
                acc[m][n][r] = 0.f;

    // ---- A-frag ring init for tile 0 (slots 0..9 = key16 -3..6) ----
    bf16x8 af[12];
#pragma unroll
    for (int kb = -3; kb <= 6; ++kb) {
        int mt = (kb <= 0) ? 0 : ((kb + 1) >> 1);
        int kk = 2 * mt - kb;
        af[kb + 3] = *(const bf16x8*)(T +
            (size_t)(i0 + wm * 128 + mt * 32 + l31) * NSEQ + kk * 16 + lhi2 * 8);
    }
    // base for fresh A-frag loads (canonical mt=0 row, per-lane)
    const unsigned short* freshBase =
        T + (size_t)(i0 + wm * 128 + l31) * NSEQ + lhi2 * 8;

    bf16x8 bfr0[4], bfr1[4];

#define READB(BF, BUF, H) { \
    const unsigned short* Bs_ = &sB[BUF][0]; \
    int row_ = wn * 64 + (H) * 32 + l31; \
    int rb_ = row_ * BK, rx_ = row_ & 7; \
    _Pragma("unroll") \
    for (int kk_ = 0; kk_ < 4; ++kk_) \
        BF[kk_] = *(const bf16x8*)&Bs_[rb_ + (((kk_ * 2 + lhi2) ^ rx_) << 3)]; \
}

// slot of frag (mt,kk) in tile with kt%3==KTM  (compile-time under unroll)
#define SLOT(MT, KK, KTM) (((2 * (MT) - (KK) - 4 * (KTM) + 3) % 12 + 12) % 12)
// slot of fresh frag j (= (mt0, kk=3-j) of tile kt+1), written in body kt
#define FSLOT(J, KTM) ((((J) - 4 * ((KTM) + 1)) % 12 + 12) % 12)

#define FRESH(KTM, KT) { \
    const unsigned short* fp_ = freshBase + ((KT) + 1) * BK; \
    af[FSLOT(0, KTM)] = *(const bf16x8*)(fp_ + 48); \
    af[FSLOT(1, KTM)] = *(const bf16x8*)(fp_ + 32); \
    af[FSLOT(2, KTM)] = *(const bf16x8*)(fp_ + 16); \
    af[FSLOT(3, KTM)] = *(const bf16x8*)(fp_ +  0); \
}

#define QCH(MT, KTM, BF, H) \
    _Pragma("unroll") \
    for (int kk_ = 0; kk_ < 4; ++kk_) \
        acc[MT][H] = __builtin_amdgcn_mfma_f32_32x32x16_bf16( \
            af[SLOT(MT, kk_, KTM)], BF[kk_], acc[MT][H], 0, 0, 0);

// Body kt: [vmcnt(0), SBAR] | readB(bfr1,kt) | Q3 Q2 (n0) | stage(kt+2) |
// Q1 Q0 (n0) | Q3 Q2 (n1) | fresh(kt+1)+readB(bfr0,kt+1) | Q1 Q0 (n1)
#define TILE_BODY(KTM, BUF, KT, DOSTAGE, DONEXT) { \
    asm volatile("s_waitcnt vmcnt(0)" ::: "memory"); \
    SBAR(); \
    __builtin_amdgcn_sched_barrier(0); \
    READB(bfr1, BUF, 1) \
    __builtin_amdgcn_s_setprio(1); \
    QCH(3, KTM, bfr0, 0) \
    QCH(2, KTM, bfr0, 0) \
    __builtin_amdgcn_s_setprio(0); \
    if (DOSTAGE) { STAGE((((KT) + 2) & 3), ((KT) + 2) * BK); } \
    __builtin_amdgcn_s_setprio(1); \
    QCH(1, KTM, bfr0, 0) \
    QCH(0, KTM, bfr0, 0) \
    QCH(3, KTM, bfr1, 1) \
    QCH(2, KTM, bfr1, 1) \
    __builtin_amdgcn_s_setprio(0); \
    if (DONEXT) { \
        FRESH(KTM, KT) \
        READB(bfr0, (((KT) + 1) & 3), 0) \
    } \
    __builtin_amdgcn_s_setprio(1); \
    QCH(1, KTM, bfr1, 1) \
    QCH(0, KTM, bfr1, 1) \
    __builtin_amdgcn_s_setprio(0); \
}

    STAGE(0, 0);
    STAGE(1, BK);
    asm volatile("s_waitcnt vmcnt(0)" ::: "memory");
    SBAR();
    __builtin_amdgcn_sched_barrier(0);
    READB(bfr0, 0, 0)

    for (int s = 0; s < 5; ++s) {
        const int kt = s * 12;
        TILE_BODY(0, 0, (kt + 0), 1, 1)
        TILE_BODY(1, 1, (kt + 1), 1, 1)
        TILE_BODY(2, 2, (kt + 2), 1, 1)
        TILE_BODY(0, 3, (kt + 3), 1, 1)
        TILE_BODY(1, 0, (kt + 4), 1, 1)
        TILE_BODY(2, 1, (kt + 5), 1, 1)
        TILE_BODY(0, 2, (kt + 6), 1, 1)
        TILE_BODY(1, 3, (kt + 7), 1, 1)
        TILE_BODY(2, 0, (kt + 8), 1, 1)
        TILE_BODY(0, 1, (kt + 9), 1, 1)
        TILE_BODY(1, 2, (kt + 10), 1, 1)
        TILE_BODY(2, 3, (kt + 11), 1, 1)
    }
    TILE_BODY(0, 0, 60, 1, 1)
    TILE_BODY(1, 1, 61, 1, 1)
    TILE_BODY(2, 2, 62, 0, 1)
    TILE_BODY(0, 3, 63, 0, 0)

#undef TILE_BODY
#undef QCH
#undef FRESH
#undef SLOT
#undef FSLOT
#undef STAGE
#undef READB

    // ---- epilogue: 32x32 C/D layout col=lane&31, row=(reg&3)+8*(reg>>2)+4*(lane>>5)
    float* outb = out + ((size_t)b * NSEQ + i0 + wm * 128) * DDIM + n0 + wn * 64;
#pragma unroll
    for (int mt = 0; mt < 4; ++mt)
#pragma unroll
        for (int n = 0; n < 2; ++n)
#pragma unroll
            for (int r = 0; r < 16; ++r) {
                int row = mt * 32 + (r & 3) + 8 * (r >> 2) + 4 * lhi2;
                outb[(size_t)row * DDIM + n * 32 + l31] = acc[mt][n][r];
            }
}

// ---------------------------------------------------------------------------
extern "C" void kernel_launch(void* const* d_in, const int* in_sizes, int n_in,
                              void* d_out, int out_size, void* d_ws, size_t ws_size,
                              hipStream_t stream) {
    const float* x    = (const float*)d_in[0];
    const float* pos  = (const float*)d_in[1];
    const float* zero = (const float*)d_in[2];
    const float* neg  = (const float*)d_in[3];
    float* out = (float*)d_out;

    unsigned short* Tm = (unsigned short*)d_ws;                    // 32 MiB
    unsigned short* xT = Tm + (size_t)NSEQ * NSEQ;                 // 32 MiB

    fused_prep<<<dim3(12288), 256, 0, stream>>>(x, pos, zero, neg, Tm, xT);
    gemm_toep32g<<<dim3(NSEQ / BMN * (DDIM / BMN) * NB), 512, 0, stream>>>(Tm, xT, out);
}

// Round 9
// 169.811 us; speedup vs baseline: 1.2209x; 1.2209x over previous
//
#include <hip/hip_runtime.h>
#include <hip/hip_bf16.h>
#include <stdint.h>

#define NSEQ 4096
#define DDIM 512
#define NB   8

#define BMN 256
#define BK  64
#define NT  (NSEQ / BK)   // 64 K-tiles

typedef float f32x16 __attribute__((ext_vector_type(16)));
typedef __bf16 bf16x8 __attribute__((ext_vector_type(8)));

typedef const void __attribute__((address_space(1))) gvoid_t;
typedef void __attribute__((address_space(3))) svoid_t;

#define SBAR() do { __builtin_amdgcn_s_barrier(); asm volatile("" ::: "memory"); } while (0)

__device__ __forceinline__ unsigned short f2bf(float f) {
    union { float f; unsigned int u; } v;
    v.f = f;
    unsigned int u = v.u;
    u += 0x7FFFu + ((u >> 16) & 1u);   // RNE
    return (unsigned short)(u >> 16);
}

// ---------------------------------------------------------------------------
// Fused prep: blocks [0,8192) build T; blocks [8192,12288) transpose x -> xT.
// ---------------------------------------------------------------------------
__global__ void fused_prep(const float* __restrict__ x,
                           const float* __restrict__ pos,
                           const float* __restrict__ zero,
                           const float* __restrict__ neg,
                           unsigned short* __restrict__ T,
                           unsigned short* __restrict__ xT) {
    __shared__ unsigned short tl[64][72];
    if (blockIdx.x < 8192) {
        int tid = blockIdx.x * 256 + threadIdx.x;
        int i  = tid >> 9;
        int j0 = (tid & 511) << 3;
        float z = zero[0];
        unsigned short r[8];
#pragma unroll
        for (int e = 0; e < 8; ++e) {
            int j = j0 + e;
            int d = i - j;
            float v;
            if (d > 0)       v = pos[d - 1];
            else if (d == 0) v = z;
            else             v = neg[NSEQ - 1 + d];
            v = fminf(fmaxf(v, -60.0f), 30.0f);
            r[e] = f2bf(__expf(v));
        }
        uint4 o;
        o.x = (unsigned int)r[0] | ((unsigned int)r[1] << 16);
        o.y = (unsigned int)r[2] | ((unsigned int)r[3] << 16);
        o.z = (unsigned int)r[4] | ((unsigned int)r[5] << 16);
        o.w = (unsigned int)r[6] | ((unsigned int)r[7] << 16);
        *(uint4*)(T + (size_t)i * NSEQ + j0) = o;
    } else {
        int t   = blockIdx.x - 8192;        // 0..4095
        int b   = t >> 9;
        int rem = t & 511;
        int j0  = (rem >> 3) << 6;
        int d0  = (rem & 7) << 6;
        const float* xb = x + (size_t)b * NSEQ * DDIM;
#pragma unroll
        for (int e = 0; e < 4; ++e) {
            int idx = e * 256 + threadIdx.x;    // 0..1023
            int r   = idx >> 4;                 // j offset 0..63
            int c4  = (idx & 15) << 2;          // d offset (x4)
            float4 v = *(const float4*)&xb[(size_t)(j0 + r) * DDIM + d0 + c4];
            ushort4 o;
            o.x = f2bf(v.x); o.y = f2bf(v.y); o.z = f2bf(v.z); o.w = f2bf(v.w);
            *(ushort4*)&tl[r][c4] = o;
        }
        __syncthreads();
        unsigned short* xtb = xT + (size_t)b * DDIM * NSEQ;
#pragma unroll
        for (int e = 0; e < 4; ++e) {
            int idx = e * 256 + threadIdx.x;
            int d   = idx >> 4;                 // d offset 0..63
            int jq  = (idx & 15) << 2;          // j offset (x4)
            ushort4 o;
            o.x = tl[jq + 0][d]; o.y = tl[jq + 1][d];
            o.z = tl[jq + 2][d]; o.w = tl[jq + 3][d];
            *(ushort4*)&xtb[(size_t)(d0 + d) * NSEQ + j0 + jq] = o;
        }
    }
}

// ---------------------------------------------------------------------------
// GEMM: out[b] = T @ x[b].  32x32x16 MFMA, Toeplitz A-register-ring refreshed
// from GLOBAL T.  sB: 4 buffers.  Issue order per tile kt:
//   vmcnt(4) [drains stage(kt+1), leaves fresh(kt)] ; SBAR
//   readB(bfr1,kt) ; STAGE(kt+2) ; Q3(n0) Q3(n1)
//   FRESH(kt+1)   [slots expire at Q3]
//   Q2 Q1 Q0 (n0), Q2(n1) ; readB(bfr0,kt+1) ; Q1 Q0 (n1)
// One counted vmcnt + one barrier per tile; no lgkm drains; never vmcnt(0).
// ---------------------------------------------------------------------------
__global__ __launch_bounds__(512, 2) void gemm_toep32r(
        const unsigned short* __restrict__ T,    // [NSEQ][NSEQ] bf16
        const unsigned short* __restrict__ xT,   // [NB][DDIM][NSEQ] bf16
        float* __restrict__ out) {               // [NB][NSEQ][DDIM] f32
    __shared__ __attribute__((aligned(16))) unsigned short sB[4][BMN * BK];  // 32 KB x4

    const int tid  = threadIdx.x;
    const int lane = tid & 63;
    const int wid  = tid >> 6;      // 0..7
    const int wm   = wid >> 2;      // 0..1 -> 128-row half
    const int wn   = wid & 3;       // 0..3 -> 64-col quarter
    const int l31  = lane & 31;
    const int lhi2 = lane >> 5;     // 0..1

    // ---- XCD-aware bijective block swizzle (256 blocks, 8 XCDs) ----
    int lin = blockIdx.x;
    int swz = (lin & 7) * 32 + (lin >> 3);
    int it  = swz >> 4;
    int tn  = (swz & 15) & 1;
    int b   = (swz & 15) >> 1;
    const int i0 = it * BMN;
    const int n0 = tn * BMN;

    const unsigned short* Bg = xT + ((size_t)b * DDIM + n0) * NSEQ;

    // staging geometry: 8 rows x 128B per instr, pre-swizzled source chunk
    const int srow = lane >> 3;
    const int schk = (lane & 7) ^ srow;
    uint32_t offB[4];
#pragma unroll
    for (int q = 0; q < 4; ++q)
        offB[q] = (uint32_t)((q * 8 + wid) * 8 + srow) * NSEQ + schk * 8;

#define STAGE(BUF, K0) do { \
    _Pragma("unroll") \
    for (int q_ = 0; q_ < 4; ++q_) \
        __builtin_amdgcn_global_load_lds( \
            (gvoid_t*)(const void*)(Bg + offB[q_] + (K0)), \
            (svoid_t*)(void*)(&sB[BUF][0] + (q_ * 8 + wid) * 512), 16, 0, 0); \
} while (0)

    f32x16 acc[4][2];
#pragma unroll
    for (int m = 0; m < 4; ++m)
#pragma unroll
        for (int n = 0; n < 2; ++n)
#pragma unroll
            for (int r = 0; r < 16; ++r)
                acc[m][n][r] = 0.f;

    // ---- A-frag ring init for tile 0 (slots 0..9 = key16 -3..6) ----
    bf16x8 af[12];
#pragma unroll
    for (int kb = -3; kb <= 6; ++kb) {
        int mt = (kb <= 0) ? 0 : ((kb + 1) >> 1);
        int kk = 2 * mt - kb;
        af[kb + 3] = *(const bf16x8*)(T +
            (size_t)(i0 + wm * 128 + mt * 32 + l31) * NSEQ + kk * 16 + lhi2 * 8);
    }
    // base for fresh A-frag loads (canonical mt=0 row, per-lane)
    const unsigned short* freshBase =
        T + (size_t)(i0 + wm * 128 + l31) * NSEQ + lhi2 * 8;

    bf16x8 bfr0[4], bfr1[4];

#define READB(BF, BUF, H) { \
    const unsigned short* Bs_ = &sB[BUF][0]; \
    int row_ = wn * 64 + (H) * 32 + l31; \
    int rb_ = row_ * BK, rx_ = row_ & 7; \
    _Pragma("unroll") \
    for (int kk_ = 0; kk_ < 4; ++kk_) \
        BF[kk_] = *(const bf16x8*)&Bs_[rb_ + (((kk_ * 2 + lhi2) ^ rx_) << 3)]; \
}

// slot of frag (mt,kk) in tile with kt%3==KTM  (compile-time under unroll)
#define SLOT(MT, KK, KTM) (((2 * (MT) - (KK) - 4 * (KTM) + 3) % 12 + 12) % 12)
// slot of fresh frag j (= (mt0, kk=3-j) of tile kt+1), written in body kt
#define FSLOT(J, KTM) ((((J) - 4 * ((KTM) + 1)) % 12 + 12) % 12)

#define FRESH(KTM, KT) { \
    const unsigned short* fp_ = freshBase + ((KT) + 1) * BK; \
    af[FSLOT(0, KTM)] = *(const bf16x8*)(fp_ + 48); \
    af[FSLOT(1, KTM)] = *(const bf16x8*)(fp_ + 32); \
    af[FSLOT(2, KTM)] = *(const bf16x8*)(fp_ + 16); \
    af[FSLOT(3, KTM)] = *(const bf16x8*)(fp_ +  0); \
}

#define QCH(MT, KTM, BF, H) \
    _Pragma("unroll") \
    for (int kk_ = 0; kk_ < 4; ++kk_) \
        acc[MT][H] = __builtin_amdgcn_mfma_f32_32x32x16_bf16( \
            af[SLOT(MT, kk_, KTM)], BF[kk_], acc[MT][H], 0, 0, 0);

#define TILE_BODY(KTM, BUF, KT, DOSTAGE, DONEXT) { \
    asm volatile("s_waitcnt vmcnt(4)" ::: "memory"); \
    SBAR(); \
    __builtin_amdgcn_sched_barrier(0); \
    READB(bfr1, BUF, 1) \
    if (DOSTAGE) { STAGE((((KT) + 2) & 3), ((KT) + 2) * BK); } \
    __builtin_amdgcn_s_setprio(1); \
    QCH(3, KTM, bfr0, 0) \
    QCH(3, KTM, bfr1, 1) \
    __builtin_amdgcn_s_setprio(0); \
    if (DONEXT) { FRESH(KTM, KT) } \
    __builtin_amdgcn_sched_barrier(0); \
    __builtin_amdgcn_s_setprio(1); \
    QCH(2, KTM, bfr0, 0) \
    QCH(1, KTM, bfr0, 0) \
    QCH(0, KTM, bfr0, 0) \
    QCH(2, KTM, bfr1, 1) \
    __builtin_amdgcn_s_setprio(0); \
    if (DONEXT) { READB(bfr0, (((KT) + 1) & 3), 0) } \
    __builtin_amdgcn_s_setprio(1); \
    QCH(1, KTM, bfr1, 1) \
    QCH(0, KTM, bfr1, 1) \
    __builtin_amdgcn_s_setprio(0); \
}

    STAGE(0, 0);
    STAGE(1, BK);
    asm volatile("s_waitcnt vmcnt(0)" ::: "memory");
    SBAR();
    __builtin_amdgcn_sched_barrier(0);
    READB(bfr0, 0, 0)

    for (int s = 0; s < 5; ++s) {
        const int kt = s * 12;
        TILE_BODY(0, 0, (kt + 0), 1, 1)
        TILE_BODY(1, 1, (kt + 1), 1, 1)
        TILE_BODY(2, 2, (kt + 2), 1, 1)
        TILE_BODY(0, 3, (kt + 3), 1, 1)
        TILE_BODY(1, 0, (kt + 4), 1, 1)
        TILE_BODY(2, 1, (kt + 5), 1, 1)
        TILE_BODY(0, 2, (kt + 6), 1, 1)
        TILE_BODY(1, 3, (kt + 7), 1, 1)
        TILE_BODY(2, 0, (kt + 8), 1, 1)
        TILE_BODY(0, 1, (kt + 9), 1, 1)
        TILE_BODY(1, 2, (kt + 10), 1, 1)
        TILE_BODY(2, 3, (kt + 11), 1, 1)
    }
    TILE_BODY(0, 0, 60, 1, 1)
    TILE_BODY(1, 1, 61, 1, 1)
    TILE_BODY(2, 2, 62, 0, 1)
    TILE_BODY(0, 3, 63, 0, 0)

#undef TILE_BODY
#undef QCH
#undef FRESH
#undef SLOT
#undef FSLOT
#undef STAGE
#undef READB

    // ---- epilogue: 32x32 C/D layout col=lane&31, row=(reg&3)+8*(reg>>2)+4*(lane>>5)
    float* outb = out + ((size_t)b * NSEQ + i0 + wm * 128) * DDIM + n0 + wn * 64;
#pragma unroll
    for (int mt = 0; mt < 4; ++mt)
#pragma unroll
        for (int n = 0; n < 2; ++n)
#pragma unroll
            for (int r = 0; r < 16; ++r) {
                int row = mt * 32 + (r & 3) + 8 * (r >> 2) + 4 * lhi2;
                outb[(size_t)row * DDIM + n * 32 + l31] = acc[mt][n][r];
            }
}

// ---------------------------------------------------------------------------
extern "C" void kernel_launch(void* const* d_in, const int* in_sizes, int n_in,
                              void* d_out, int out_size, void* d_ws, size_t ws_size,
                              hipStream_t stream) {
    const float* x    = (const float*)d_in[0];
    const float* pos  = (const float*)d_in[1];
    const float* zero = (const float*)d_in[2];
    const float* neg  = (const float*)d_in[3];
    float* out = (float*)d_out;

    unsigned short* Tm = (unsigned short*)d_ws;                    // 32 MiB
    unsigned short* xT = Tm + (size_t)NSEQ * NSEQ;                 // 32 MiB

    fused_prep<<<dim3(12288), 256, 0, stream>>>(x, pos, zero, neg, Tm, xT);
    gemm_toep32r<<<dim3(NSEQ / BMN * (DDIM / BMN) * NB), 512, 0, stream>>>(Tm, xT, out);
}

// Round 10
// 169.255 us; speedup vs baseline: 1.2249x; 1.0033x over previous
//
#include <hip/hip_runtime.h>
#include <hip/hip_bf16.h>
#include <stdint.h>

#define NSEQ 4096
#define DDIM 512
#define NB   8

#define BK  64
#define NT  (NSEQ / BK)   // 64 K-tiles

typedef float f32x16 __attribute__((ext_vector_type(16)));
typedef __bf16 bf16x8 __attribute__((ext_vector_type(8)));

typedef const void __attribute__((address_space(1))) gvoid_t;
typedef void __attribute__((address_space(3))) svoid_t;

#define SBAR() do { __builtin_amdgcn_s_barrier(); asm volatile("" ::: "memory"); } while (0)

__device__ __forceinline__ unsigned short f2bf(float f) {
    union { float f; unsigned int u; } v;
    v.f = f;
    unsigned int u = v.u;
    u += 0x7FFFu + ((u >> 16) & 1u);   // RNE
    return (unsigned short)(u >> 16);
}

// ---------------------------------------------------------------------------
// Fused prep: blocks [0,8192) build T; blocks [8192,12288) transpose x -> xT.
// ---------------------------------------------------------------------------
__global__ void fused_prep(const float* __restrict__ x,
                           const float* __restrict__ pos,
                           const float* __restrict__ zero,
                           const float* __restrict__ neg,
                           unsigned short* __restrict__ T,
                           unsigned short* __restrict__ xT) {
    __shared__ unsigned short tl[64][72];
    if (blockIdx.x < 8192) {
        int tid = blockIdx.x * 256 + threadIdx.x;
        int i  = tid >> 9;
        int j0 = (tid & 511) << 3;
        float z = zero[0];
        unsigned short r[8];
#pragma unroll
        for (int e = 0; e < 8; ++e) {
            int j = j0 + e;
            int d = i - j;
            float v;
            if (d > 0)       v = pos[d - 1];
            else if (d == 0) v = z;
            else             v = neg[NSEQ - 1 + d];
            v = fminf(fmaxf(v, -60.0f), 30.0f);
            r[e] = f2bf(__expf(v));
        }
        uint4 o;
        o.x = (unsigned int)r[0] | ((unsigned int)r[1] << 16);
        o.y = (unsigned int)r[2] | ((unsigned int)r[3] << 16);
        o.z = (unsigned int)r[4] | ((unsigned int)r[5] << 16);
        o.w = (unsigned int)r[6] | ((unsigned int)r[7] << 16);
        *(uint4*)(T + (size_t)i * NSEQ + j0) = o;
    } else {
        int t   = blockIdx.x - 8192;        // 0..4095
        int b   = t >> 9;
        int rem = t & 511;
        int j0  = (rem >> 3) << 6;
        int d0  = (rem & 7) << 6;
        const float* xb = x + (size_t)b * NSEQ * DDIM;
#pragma unroll
        for (int e = 0; e < 4; ++e) {
            int idx = e * 256 + threadIdx.x;    // 0..1023
            int r   = idx >> 4;                 // j offset 0..63
            int c4  = (idx & 15) << 2;          // d offset (x4)
            float4 v = *(const float4*)&xb[(size_t)(j0 + r) * DDIM + d0 + c4];
            ushort4 o;
            o.x = f2bf(v.x); o.y = f2bf(v.y); o.z = f2bf(v.z); o.w = f2bf(v.w);
            *(ushort4*)&tl[r][c4] = o;
        }
        __syncthreads();
        unsigned short* xtb = xT + (size_t)b * DDIM * NSEQ;
#pragma unroll
        for (int e = 0; e < 4; ++e) {
            int idx = e * 256 + threadIdx.x;
            int d   = idx >> 4;                 // d offset 0..63
            int jq  = (idx & 15) << 2;          // j offset (x4)
            ushort4 o;
            o.x = tl[jq + 0][d]; o.y = tl[jq + 1][d];
            o.z = tl[jq + 2][d]; o.w = tl[jq + 3][d];
            *(ushort4*)&xtb[(size_t)(d0 + d) * NSEQ + j0 + jq] = o;
        }
    }
}

// ---------------------------------------------------------------------------
// GEMM: out[b] = T @ x[b].  32x32x16 MFMA, Toeplitz A-register-ring from
// global T.  256-THREAD blocks (4 waves, 2M x 2N, block tile 256x128),
// sB = 4 x 16 KB = 64 KB  ->  TWO blocks per CU = two independent barrier
// domains; block B's waves feed the matrix pipe while block A drains.
// Per tile: vmcnt(4)+SBAR | readB(bfr1) | STAGE(kt+2) | Q3 | FRESH(kt+1) |
// Q2..Q0(n0),Q2(n1) | readB(bfr0,kt+1) | Q1,Q0(n1).  Never vmcnt(0).
// ---------------------------------------------------------------------------
__global__ __launch_bounds__(256, 2) void gemm_toep32d(
        const unsigned short* __restrict__ T,    // [NSEQ][NSEQ] bf16
        const unsigned short* __restrict__ xT,   // [NB][DDIM][NSEQ] bf16
        float* __restrict__ out) {               // [NB][NSEQ][DDIM] f32
    __shared__ __attribute__((aligned(16))) unsigned short sB[4][128 * BK];  // 16 KB x4

    const int tid  = threadIdx.x;
    const int lane = tid & 63;
    const int wid  = tid >> 6;      // 0..3
    const int wm   = wid >> 1;      // 0..1 -> 128-row half
    const int wn   = wid & 1;       // 0..1 -> 64-col half
    const int l31  = lane & 31;
    const int lhi2 = lane >> 5;     // 0..1

    // ---- XCD-aware bijective block swizzle (512 blocks, 8 XCDs) ----
    int lin = blockIdx.x;
    int swz = (lin & 7) * 64 + (lin >> 3);
    int it  = swz >> 5;             // i-tile 0..15
    int rem = swz & 31;
    int nb  = rem >> 3;             // n-block 0..3
    int b   = rem & 7;              // batch 0..7
    const int i0 = it * 256;
    const int n0 = nb * 128;

    const unsigned short* Bg = xT + ((size_t)b * DDIM + n0) * NSEQ;

    // staging geometry: 8 rows x 128B per instr, pre-swizzled source chunk
    const int srow = lane >> 3;
    const int schk = (lane & 7) ^ srow;
    uint32_t offB[4];
#pragma unroll
    for (int q = 0; q < 4; ++q)
        offB[q] = (uint32_t)((q * 4 + wid) * 8 + srow) * NSEQ + schk * 8;

#define STAGE(BUF, K0) do { \
    _Pragma("unroll") \
    for (int q_ = 0; q_ < 4; ++q_) \
        __builtin_amdgcn_global_load_lds( \
            (gvoid_t*)(const void*)(Bg + offB[q_] + (K0)), \
            (svoid_t*)(void*)(&sB[BUF][0] + (q_ * 4 + wid) * 512), 16, 0, 0); \
} while (0)

    f32x16 acc[4][2];
#pragma unroll
    for (int m = 0; m < 4; ++m)
#pragma unroll
        for (int n = 0; n < 2; ++n)
#pragma unroll
            for (int r = 0; r < 16; ++r)
                acc[m][n][r] = 0.f;

    // ---- A-frag ring init for tile 0 (slots 0..9 = key16 -3..6) ----
    bf16x8 af[12];
#pragma unroll
    for (int kb = -3; kb <= 6; ++kb) {
        int mt = (kb <= 0) ? 0 : ((kb + 1) >> 1);
        int kk = 2 * mt - kb;
        af[kb + 3] = *(const bf16x8*)(T +
            (size_t)(i0 + wm * 128 + mt * 32 + l31) * NSEQ + kk * 16 + lhi2 * 8);
    }
    // base for fresh A-frag loads (canonical mt=0 rows, per-lane)
    const unsigned short* freshBase =
        T + (size_t)(i0 + wm * 128 + l31) * NSEQ + lhi2 * 8;

    bf16x8 bfr0[4], bfr1[4];

#define READB(BF, BUF, H) { \
    const unsigned short* Bs_ = &sB[BUF][0]; \
    int row_ = wn * 64 + (H) * 32 + l31; \
    int rb_ = row_ * BK, rx_ = row_ & 7; \
    _Pragma("unroll") \
    for (int kk_ = 0; kk_ < 4; ++kk_) \
        BF[kk_] = *(const bf16x8*)&Bs_[rb_ + (((kk_ * 2 + lhi2) ^ rx_) << 3)]; \
}

// slot of frag (mt,kk) in tile with kt%3==KTM  (compile-time under unroll)
#define SLOT(MT, KK, KTM) (((2 * (MT) - (KK) - 4 * (KTM) + 3) % 12 + 12) % 12)
// slot of fresh frag j (= (mt0, kk=3-j) of tile kt+1), written in body kt
#define FSLOT(J, KTM) ((((J) - 4 * ((KTM) + 1)) % 12 + 12) % 12)

#define FRESH(KTM, KT) { \
    const unsigned short* fp_ = freshBase + ((KT) + 1) * BK; \
    af[FSLOT(0, KTM)] = *(const bf16x8*)(fp_ + 48); \
    af[FSLOT(1, KTM)] = *(const bf16x8*)(fp_ + 32); \
    af[FSLOT(2, KTM)] = *(const bf16x8*)(fp_ + 16); \
    af[FSLOT(3, KTM)] = *(const bf16x8*)(fp_ +  0); \
}

#define QCH(MT, KTM, BF, H) \
    _Pragma("unroll") \
    for (int kk_ = 0; kk_ < 4; ++kk_) \
        acc[MT][H] = __builtin_amdgcn_mfma_f32_32x32x16_bf16( \
            af[SLOT(MT, kk_, KTM)], BF[kk_], acc[MT][H], 0, 0, 0);

#define TILE_BODY(KTM, BUF, KT, DOSTAGE, DONEXT) { \
    asm volatile("s_waitcnt vmcnt(4)" ::: "memory"); \
    SBAR(); \
    __builtin_amdgcn_sched_barrier(0); \
    READB(bfr1, BUF, 1) \
    if (DOSTAGE) { STAGE((((KT) + 2) & 3), ((KT) + 2) * BK); } \
    __builtin_amdgcn_s_setprio(1); \
    QCH(3, KTM, bfr0, 0) \
    QCH(3, KTM, bfr1, 1) \
    __builtin_amdgcn_s_setprio(0); \
    if (DONEXT) { FRESH(KTM, KT) } \
    __builtin_amdgcn_sched_barrier(0); \
    __builtin_amdgcn_s_setprio(1); \
    QCH(2, KTM, bfr0, 0) \
    QCH(1, KTM, bfr0, 0) \
    QCH(0, KTM, bfr0, 0) \
    QCH(2, KTM, bfr1, 1) \
    __builtin_amdgcn_s_setprio(0); \
    if (DONEXT) { READB(bfr0, (((KT) + 1) & 3), 0) } \
    __builtin_amdgcn_s_setprio(1); \
    QCH(1, KTM, bfr1, 1) \
    QCH(0, KTM, bfr1, 1) \
    __builtin_amdgcn_s_setprio(0); \
}

    STAGE(0, 0);
    STAGE(1, BK);
    asm volatile("s_waitcnt vmcnt(0)" ::: "memory");
    SBAR();
    __builtin_amdgcn_sched_barrier(0);
    READB(bfr0, 0, 0)

    for (int s = 0; s < 5; ++s) {
        const int kt = s * 12;
        TILE_BODY(0, 0, (kt + 0), 1, 1)
        TILE_BODY(1, 1, (kt + 1), 1, 1)
        TILE_BODY(2, 2, (kt + 2), 1, 1)
        TILE_BODY(0, 3, (kt + 3), 1, 1)
        TILE_BODY(1, 0, (kt + 4), 1, 1)
        TILE_BODY(2, 1, (kt + 5), 1, 1)
        TILE_BODY(0, 2, (kt + 6), 1, 1)
        TILE_BODY(1, 3, (kt + 7), 1, 1)
        TILE_BODY(2, 0, (kt + 8), 1, 1)
        TILE_BODY(0, 1, (kt + 9), 1, 1)
        TILE_BODY(1, 2, (kt + 10), 1, 1)
        TILE_BODY(2, 3, (kt + 11), 1, 1)
    }
    TILE_BODY(0, 0, 60, 1, 1)
    TILE_BODY(1, 1, 61, 1, 1)
    TILE_BODY(2, 2, 62, 0, 1)
    TILE_BODY(0, 3, 63, 0, 0)

#undef TILE_BODY
#undef QCH
#undef FRESH
#undef SLOT
#undef FSLOT
#undef STAGE
#undef READB

    // ---- epilogue: 32x32 C/D layout col=lane&31, row=(reg&3)+8*(reg>>2)+4*(lane>>5)
    float* outb = out + ((size_t)b * NSEQ + i0 + wm * 128) * DDIM + n0 + wn * 64;
#pragma unroll
    for (int mt = 0; mt < 4; ++mt)
#pragma unroll
        for (int n = 0; n < 2; ++n)
#pragma unroll
            for (int r = 0; r < 16; ++r) {
                int row = mt * 32 + (r & 3) + 8 * (r >> 2) + 4 * lhi2;
                outb[(size_t)row * DDIM + n * 32 + l31] = acc[mt][n][r];
            }
}

// ---------------------------------------------------------------------------
extern "C" void kernel_launch(void* const* d_in, const int* in_sizes, int n_in,
                              void* d_out, int out_size, void* d_ws, size_t ws_size,
                              hipStream_t stream) {
    const float* x    = (const float*)d_in[0];
    const float* pos  = (const float*)d_in[1];
    const float* zero = (const float*)d_in[2];
    const float* neg  = (const float*)d_in[3];
    float* out = (float*)d_out;

    unsigned short* Tm = (unsigned short*)d_ws;                    // 32 MiB
    unsigned short* xT = Tm + (size_t)NSEQ * NSEQ;                 // 32 MiB

    fused_prep<<<dim3(12288), 256, 0, stream>>>(x, pos, zero, neg, Tm, xT);
    gemm_toep32d<<<dim3(16 * 4 * NB), 256, 0, stream>>>(Tm, xT, out);
}

// Round 11
// 153.748 us; speedup vs baseline: 1.3485x; 1.1009x over previous
//
#include <hip/hip_runtime.h>
#include <hip/hip_bf16.h>
#include <stdint.h>

#define NSEQ 4096
#define DDIM 512
#define NB   8
#define FN   8192          // FFT length = 2*NSEQ

#define PADI(i) ((i) + ((i) >> 5))

struct __align__(8) cf { float x, y; };

__device__ __forceinline__ cf cadd(cf a, cf b) { return {a.x + b.x, a.y + b.y}; }
__device__ __forceinline__ cf csub(cf a, cf b) { return {a.x - b.x, a.y - b.y}; }
__device__ __forceinline__ cf cmul(cf a, cf b) {
    return {a.x * b.x - a.y * b.y, a.x * b.y + a.y * b.x};
}
template<int DIR> __device__ __forceinline__ cf crot(cf z) {  // *(-i) fwd, *(+i) inv
    return DIR < 0 ? cf{z.y, -z.x} : cf{-z.y, z.x};
}

__device__ __forceinline__ unsigned short f2bf(float f) {
    union { float f; unsigned int u; } v;
    v.f = f;
    unsigned int u = v.u;
    u += 0x7FFFu + ((u >> 16) & 1u);   // RNE
    return (unsigned short)(u >> 16);
}
__device__ __forceinline__ float bf2f(unsigned short u) {
    union { unsigned int i; float f; } v;
    v.i = (unsigned int)u << 16;
    return v.f;
}

// ---------------------------------------------------------------------------
// 8-point DFT (DIR=-1 fwd: W8 = e^{-i pi/4}; DIR=+1 unscaled inverse: conj)
// ---------------------------------------------------------------------------
template<int DIR>
__device__ __forceinline__ void fft4(cf& b0, cf& b1, cf& b2, cf& b3) {
    cf s0 = cadd(b0, b2), s1 = csub(b0, b2);
    cf s2 = cadd(b1, b3), s3 = crot<DIR>(csub(b1, b3));
    b0 = cadd(s0, s2); b1 = cadd(s1, s3);
    b2 = csub(s0, s2); b3 = csub(s1, s3);
}

template<int DIR>
__device__ __forceinline__ void dft8(cf a[8]) {
    cf e0 = a[0], e1 = a[2], e2 = a[4], e3 = a[6];
    cf o0 = a[1], o1 = a[3], o2 = a[5], o3 = a[7];
    fft4<DIR>(e0, e1, e2, e3);
    fft4<DIR>(o0, o1, o2, o3);
    const float c = 0.70710678118654752f;
    cf w1 = (DIR < 0) ? cf{c, -c} : cf{c, c};
    cf w3 = (DIR < 0) ? cf{-c, -c} : cf{-c, c};
    o1 = cmul(o1, w1);
    o2 = crot<DIR>(o2);
    o3 = cmul(o3, w3);
    a[0] = cadd(e0, o0); a[1] = cadd(e1, o1); a[2] = cadd(e2, o2); a[3] = cadd(e3, o3);
    a[4] = csub(e0, o0); a[5] = csub(e1, o1); a[6] = csub(e2, o2); a[7] = csub(e3, o3);
}

// ---------------------------------------------------------------------------
// One radix-8 stage over LDS, in place.  1024 butterflies, 256 threads.
// Fwd (DIR=-1, DIF): DFT8 then twiddle W_M^{jk}.  Inv (DIR=+1, DIT): twiddle
// W_M^{+jk} then unscaled IDFT8.  m = 1<<lm, M = 8m.
// ---------------------------------------------------------------------------
template<int DIR>
__device__ __forceinline__ void r8_stage(cf* Z, int lm, int tid) {
    const int m = 1 << lm;
    const float ang0 = ((DIR < 0) ? -6.2831853071795865f : 6.2831853071795865f)
                       / (float)(m * 8);
#pragma unroll
    for (int q = 0; q < 4; ++q) {
        int beta = q * 256 + tid;
        int j = beta & (m - 1);
        int g = beta >> lm;
        int base = (g << (lm + 3)) + j;
        cf a[8];
#pragma unroll
        for (int r = 0; r < 8; ++r) a[r] = Z[PADI(base + (r << lm))];
        float sn, cs;
        __sincosf(ang0 * (float)j, &sn, &cs);
        cf w1 = {cs, sn};
        if (DIR > 0) {
            cf wk = w1;
#pragma unroll
            for (int k = 1; k < 8; ++k) { a[k] = cmul(a[k], wk); wk = cmul(wk, w1); }
        }
        dft8<DIR>(a);
        if (DIR < 0) {
            cf wk = w1;
#pragma unroll
            for (int k = 1; k < 8; ++k) { a[k] = cmul(a[k], wk); wk = cmul(wk, w1); }
        }
#pragma unroll
        for (int r = 0; r < 8; ++r) Z[PADI(base + (r << lm))] = a[r];
    }
}

// radix-2 stage on adjacent pairs (self-inverse up to factor 2; no twiddle)
__device__ __forceinline__ void r2_stage(cf* Z, int tid) {
#pragma unroll
    for (int q = 0; q < 16; ++q) {
        int beta = q * 256 + tid;
        int i0 = PADI(2 * beta), i1 = PADI(2 * beta + 1);
        cf a = Z[i0], b = Z[i1];
        Z[i0] = cadd(a, b);
        Z[i1] = csub(a, b);
    }
}

#define FWD_CHAIN(Z, tid) \
    r8_stage<-1>(Z, 10, tid); __syncthreads(); \
    r8_stage<-1>(Z, 7,  tid); __syncthreads(); \
    r8_stage<-1>(Z, 4,  tid); __syncthreads(); \
    r8_stage<-1>(Z, 1,  tid); __syncthreads(); \
    r2_stage(Z, tid);         __syncthreads();

#define INV_CHAIN(Z, tid) \
    r2_stage(Z, tid);         __syncthreads(); \
    r8_stage<1>(Z, 1,  tid);  __syncthreads(); \
    r8_stage<1>(Z, 4,  tid);  __syncthreads(); \
    r8_stage<1>(Z, 7,  tid);  __syncthreads(); \
    r8_stage<1>(Z, 10, tid);  __syncthreads();

// ---------------------------------------------------------------------------
// Kernel 1: transpose+convert  xT[b][d][j] = bf16(x[b][j][d]).  4096 blocks.
// ---------------------------------------------------------------------------
__global__ void transpose_x(const float* __restrict__ x,
                            unsigned short* __restrict__ xT) {
    __shared__ unsigned short tl[64][72];
    int t   = blockIdx.x;
    int b   = t >> 9;
    int rem = t & 511;
    int j0  = (rem >> 3) << 6;
    int d0  = (rem & 7) << 6;
    const float* xb = x + (size_t)b * NSEQ * DDIM;
#pragma unroll
    for (int e = 0; e < 4; ++e) {
        int idx = e * 256 + threadIdx.x;
        int r   = idx >> 4;
        int c4  = (idx & 15) << 2;
        float4 v = *(const float4*)&xb[(size_t)(j0 + r) * DDIM + d0 + c4];
        ushort4 o;
        o.x = f2bf(v.x); o.y = f2bf(v.y); o.z = f2bf(v.z); o.w = f2bf(v.w);
        *(ushort4*)&tl[r][c4] = o;
    }
    __syncthreads();
    unsigned short* xtb = xT + (size_t)b * DDIM * NSEQ;
#pragma unroll
    for (int e = 0; e < 4; ++e) {
        int idx = e * 256 + threadIdx.x;
        int d   = idx >> 4;
        int jq  = (idx & 15) << 2;
        ushort4 o;
        o.x = tl[jq + 0][d]; o.y = tl[jq + 1][d];
        o.z = tl[jq + 2][d]; o.w = tl[jq + 3][d];
        *(ushort4*)&xtb[(size_t)(d0 + d) * NSEQ + j0 + jq] = o;
    }
}

// ---------------------------------------------------------------------------
// Kernel 2: build V-hat = DIF-FFT of exp(clamp(kernel)), stored digit-reversed
// (raw post-DIF order).  ONE block.
// ---------------------------------------------------------------------------
__global__ __launch_bounds__(256) void build_V(const float* __restrict__ pos,
                                               const float* __restrict__ zero,
                                               const float* __restrict__ neg,
                                               cf* __restrict__ Vh) {
    __shared__ cf Z[PADI(FN)];
    int tid = threadIdx.x;
    float zv = zero[0];
#pragma unroll
    for (int q = 0; q < 32; ++q) {
        int t = q * 256 + tid;
        float v;
        if (t == 0 || t == NSEQ) v = zv;
        else if (t < NSEQ)       v = pos[t - 1];
        else                     v = neg[t - NSEQ - 1];
        v = fminf(fmaxf(v, -60.0f), 30.0f);
        Z[PADI(t)] = {__expf(v), 0.0f};
    }
    __syncthreads();
    FWD_CHAIN(Z, tid)
#pragma unroll
    for (int q = 0; q < 32; ++q) {
        int i = q * 256 + tid;
        Vh[i] = Z[PADI(i)];
    }
}

// ---------------------------------------------------------------------------
// Kernel 3: per column-pair FFT convolution.
// z = x_d + i*x_{d+1} (zero-padded to 8192) -> DIF-FFT -> *Vh (digit-reversed
// domain) -> DIT-IFFT -> /8192 -> Re,Im are conv(x_d), conv(x_{d+1}).
// Writes bf16 result back over its own xT slot.  2048 blocks.
// ---------------------------------------------------------------------------
__global__ __launch_bounds__(256) void fft_conv(unsigned short* __restrict__ xT,
                                                const cf* __restrict__ Vh) {
    __shared__ cf Z[PADI(FN)];
    int tid = threadIdx.x;
    int blk = blockIdx.x;
    int b   = blk >> 8;
    int dp  = blk & 255;
    unsigned short* col0 = xT + ((size_t)(b * DDIM + 2 * dp)) * NSEQ;
    unsigned short* col1 = col0 + NSEQ;

#pragma unroll
    for (int q = 0; q < 4; ++q) {
        int i4 = (q * 256 + tid) * 4;
        ushort4 u0 = *(const ushort4*)&col0[i4];
        ushort4 u1 = *(const ushort4*)&col1[i4];
        Z[PADI(i4 + 0)] = {bf2f(u0.x), bf2f(u1.x)};
        Z[PADI(i4 + 1)] = {bf2f(u0.y), bf2f(u1.y)};
        Z[PADI(i4 + 2)] = {bf2f(u0.z), bf2f(u1.z)};
        Z[PADI(i4 + 3)] = {bf2f(u0.w), bf2f(u1.w)};
    }
#pragma unroll
    for (int q = 0; q < 16; ++q) {
        int i = NSEQ + q * 256 + tid;
        Z[PADI(i)] = {0.0f, 0.0f};
    }
    __syncthreads();

    FWD_CHAIN(Z, tid)

#pragma unroll
    for (int q = 0; q < 32; ++q) {
        int i = q * 256 + tid;
        Z[PADI(i)] = cmul(Z[PADI(i)], Vh[i]);
    }
    __syncthreads();

    INV_CHAIN(Z, tid)

    const float sc = 1.0f / (float)FN;
#pragma unroll
    for (int q = 0; q < 4; ++q) {
        int i4 = (q * 256 + tid) * 4;
        cf v0 = Z[PADI(i4 + 0)], v1 = Z[PADI(i4 + 1)];
        cf v2 = Z[PADI(i4 + 2)], v3 = Z[PADI(i4 + 3)];
        ushort4 o0, o1;
        o0.x = f2bf(v0.x * sc); o0.y = f2bf(v1.x * sc);
        o0.z = f2bf(v2.x * sc); o0.w = f2bf(v3.x * sc);
        o1.x = f2bf(v0.y * sc); o1.y = f2bf(v1.y * sc);
        o1.z = f2bf(v2.y * sc); o1.w = f2bf(v3.y * sc);
        *(ushort4*)&col0[i4] = o0;
        *(ushort4*)&col1[i4] = o1;
    }
}

// ---------------------------------------------------------------------------
// Kernel 4: un-transpose  out[b][j][d] = f32(outT[b][d][j]).  grid (64,8,8).
// ---------------------------------------------------------------------------
__global__ void untranspose(const unsigned short* __restrict__ oT,
                            float* __restrict__ out) {
    __shared__ unsigned short tl[64][65];
    int j0 = blockIdx.x * 64, d0 = blockIdx.y * 64, b = blockIdx.z;
    const unsigned short* src = oT + (size_t)b * DDIM * NSEQ;
#pragma unroll
    for (int e = 0; e < 16; ++e) {
        int idx = e * 256 + threadIdx.x;
        int r = idx >> 6, c = idx & 63;              // r: d-off, c: j-off
        tl[r][c] = src[(size_t)(d0 + r) * NSEQ + j0 + c];
    }
    __syncthreads();
    float* dst = out + ((size_t)b * NSEQ + j0) * DDIM + d0;
#pragma unroll
    for (int e = 0; e < 16; ++e) {
        int idx = e * 256 + threadIdx.x;
        int r = idx >> 6, c = idx & 63;              // r: j-off, c: d-off
        dst[(size_t)r * DDIM + c] = bf2f(tl[c][r]);
    }
}

// ---------------------------------------------------------------------------
extern "C" void kernel_launch(void* const* d_in, const int* in_sizes, int n_in,
                              void* d_out, int out_size, void* d_ws, size_t ws_size,
                              hipStream_t stream) {
    const float* x    = (const float*)d_in[0];
    const float* pos  = (const float*)d_in[1];
    const float* zero = (const float*)d_in[2];
    const float* neg  = (const float*)d_in[3];
    float* out = (float*)d_out;

    unsigned short* xT = (unsigned short*)d_ws;                       // 32 MiB
    cf* Vh = (cf*)((char*)d_ws + (size_t)32 * 1024 * 1024);           // 64 KiB

    build_V<<<dim3(1), 256, 0, stream>>>(pos, zero, neg, Vh);
    transpose_x<<<dim3(4096), 256, 0, stream>>>(x, xT);
    fft_conv<<<dim3(NB * 256), 256, 0, stream>>>(xT, Vh);
    untranspose<<<dim3(64, 8, 8), 256, 0, stream>>>(xT, out);
}

// Round 12
// 129.596 us; speedup vs baseline: 1.5998x; 1.1864x over previous
//
#include <hip/hip_runtime.h>
#include <hip/hip_bf16.h>
#include <stdint.h>

#define NSEQ 4096
#define DDIM 512
#define NB   8
#define FN   8192          // FFT length = 2*NSEQ

#define PADI(i) ((i) + ((i) >> 5))

struct __align__(8) cf { float x, y; };

__device__ __forceinline__ cf cadd(cf a, cf b) { return {a.x + b.x, a.y + b.y}; }
__device__ __forceinline__ cf csub(cf a, cf b) { return {a.x - b.x, a.y - b.y}; }
__device__ __forceinline__ cf cmul(cf a, cf b) {
    return {a.x * b.x - a.y * b.y, a.x * b.y + a.y * b.x};
}
template<int DIR> __device__ __forceinline__ cf crot(cf z) {  // *(-i) fwd, *(+i) inv
    return DIR < 0 ? cf{z.y, -z.x} : cf{-z.y, z.x};
}

__device__ __forceinline__ unsigned short f2bf(float f) {
    union { float f; unsigned int u; } v;
    v.f = f;
    unsigned int u = v.u;
    u += 0x7FFFu + ((u >> 16) & 1u);   // RNE
    return (unsigned short)(u >> 16);
}
__device__ __forceinline__ float bf2f(unsigned short u) {
    union { unsigned int i; float f; } v;
    v.i = (unsigned int)u << 16;
    return v.f;
}

// ---------------------------------------------------------------------------
// 8-point DFT pieces
// ---------------------------------------------------------------------------
template<int DIR>
__device__ __forceinline__ void fft4(cf& b0, cf& b1, cf& b2, cf& b3) {
    cf s0 = cadd(b0, b2), s1 = csub(b0, b2);
    cf s2 = cadd(b1, b3), s3 = crot<DIR>(csub(b1, b3));
    b0 = cadd(s0, s2); b1 = cadd(s1, s3);
    b2 = csub(s0, s2); b3 = csub(s1, s3);
}

template<int DIR>
__device__ __forceinline__ void dft8(cf a[8]) {
    cf e0 = a[0], e1 = a[2], e2 = a[4], e3 = a[6];
    cf o0 = a[1], o1 = a[3], o2 = a[5], o3 = a[7];
    fft4<DIR>(e0, e1, e2, e3);
    fft4<DIR>(o0, o1, o2, o3);
    const float c = 0.70710678118654752f;
    cf w1 = (DIR < 0) ? cf{c, -c} : cf{c, c};
    cf w3 = (DIR < 0) ? cf{-c, -c} : cf{-c, c};
    o1 = cmul(o1, w1);
    o2 = crot<DIR>(o2);
    o3 = cmul(o3, w3);
    a[0] = cadd(e0, o0); a[1] = cadd(e1, o1); a[2] = cadd(e2, o2); a[3] = cadd(e3, o3);
    a[4] = csub(e0, o0); a[5] = csub(e1, o1); a[6] = csub(e2, o2); a[7] = csub(e3, o3);
}

// DFT8 with a[4..7] == 0 (zero-padded upper half), inputs a0..a3
template<int DIR>
__device__ __forceinline__ void dft8_half(cf a0, cf a1, cf a2, cf a3, cf a[8]) {
    cf r2 = crot<DIR>(a2), r3 = crot<DIR>(a3);
    cf e0 = cadd(a0, a2), e1 = cadd(a0, r2), e2 = csub(a0, a2), e3 = csub(a0, r2);
    cf o0 = cadd(a1, a3), o1 = cadd(a1, r3), o2 = csub(a1, a3), o3 = csub(a1, r3);
    const float c = 0.70710678118654752f;
    cf w1 = (DIR < 0) ? cf{c, -c} : cf{c, c};
    cf w3 = (DIR < 0) ? cf{-c, -c} : cf{-c, c};
    o1 = cmul(o1, w1);
    o2 = crot<DIR>(o2);
    o3 = cmul(o3, w3);
    a[0] = cadd(e0, o0); a[1] = cadd(e1, o1); a[2] = cadd(e2, o2); a[3] = cadd(e3, o3);
    a[4] = csub(e0, o0); a[5] = csub(e1, o1); a[6] = csub(e2, o2); a[7] = csub(e3, o3);
}

// depth-3 twiddle powers w[k] = w1^k, k=1..7
__device__ __forceinline__ void twpow(cf w1, cf w[8]) {
    w[1] = w1;
    w[2] = cmul(w1, w1);
    w[3] = cmul(w[2], w1);
    w[4] = cmul(w[2], w[2]);
    w[5] = cmul(w[4], w1);
    w[6] = cmul(w[4], w[2]);
    w[7] = cmul(w[4], w[3]);
}

// ---------------------------------------------------------------------------
// One radix-8 stage over LDS, in place.  1024 butterflies, NTHR threads.
// ---------------------------------------------------------------------------
template<int DIR, int NTHR>
__device__ __forceinline__ void r8_stage(cf* Z, int lm, int tid) {
    const int m = 1 << lm;
    const float ang0 = ((DIR < 0) ? -6.2831853071795865f : 6.2831853071795865f)
                       / (float)(m * 8);
#pragma unroll
    for (int q = 0; q < 1024 / NTHR; ++q) {
        int beta = q * NTHR + tid;
        int j = beta & (m - 1);
        int g = beta >> lm;
        int base = (g << (lm + 3)) + j;
        cf a[8];
#pragma unroll
        for (int r = 0; r < 8; ++r) a[r] = Z[PADI(base + (r << lm))];
        float sn, cs;
        __sincosf(ang0 * (float)j, &sn, &cs);
        cf w[8];
        twpow({cs, sn}, w);
        if (DIR > 0) {
#pragma unroll
            for (int k = 1; k < 8; ++k) a[k] = cmul(a[k], w[k]);
        }
        dft8<DIR>(a);
        if (DIR < 0) {
#pragma unroll
            for (int k = 1; k < 8; ++k) a[k] = cmul(a[k], w[k]);
        }
#pragma unroll
        for (int r = 0; r < 8; ++r) Z[PADI(base + (r << lm))] = a[r];
    }
}

// First forward stage (lm=10): upper half of Z is implicit zero — read only
// 4 inputs, half-zero DFT8, write all 8.
template<int NTHR>
__device__ __forceinline__ void r8_first(cf* Z, int tid) {
    const float ang0 = -6.2831853071795865f / 8192.0f;
#pragma unroll
    for (int q = 0; q < 1024 / NTHR; ++q) {
        int j = q * NTHR + tid;
        cf a0 = Z[PADI(j)],        a1 = Z[PADI(j + 1024)];
        cf a2 = Z[PADI(j + 2048)], a3 = Z[PADI(j + 3072)];
        cf a[8];
        dft8_half<-1>(a0, a1, a2, a3, a);
        float sn, cs;
        __sincosf(ang0 * (float)j, &sn, &cs);
        cf w[8];
        twpow({cs, sn}, w);
#pragma unroll
        for (int k = 1; k < 8; ++k) a[k] = cmul(a[k], w[k]);
#pragma unroll
        for (int r = 0; r < 8; ++r) Z[PADI(j + (r << 10))] = a[r];
    }
}

// radix-2 stage on adjacent pairs (used only in build_V's full chain)
template<int NTHR>
__device__ __forceinline__ void r2_stage(cf* Z, int tid) {
#pragma unroll
    for (int q = 0; q < 4096 / NTHR; ++q) {
        int beta = q * NTHR + tid;
        int i0 = PADI(2 * beta), i1 = i0 + 1;
        cf a = Z[i0], b = Z[i1];
        Z[i0] = cadd(a, b);
        Z[i1] = csub(a, b);
    }
}

// ---------------------------------------------------------------------------
// Kernel 1: transpose+convert  xT[b][d][j] = bf16(x[b][j][d]).  4096 blocks.
// ---------------------------------------------------------------------------
__global__ void transpose_x(const float* __restrict__ x,
                            unsigned short* __restrict__ xT) {
    __shared__ unsigned short tl[64][72];
    int t   = blockIdx.x;
    int b   = t >> 9;
    int rem = t & 511;
    int j0  = (rem >> 3) << 6;
    int d0  = (rem & 7) << 6;
    const float* xb = x + (size_t)b * NSEQ * DDIM;
#pragma unroll
    for (int e = 0; e < 4; ++e) {
        int idx = e * 256 + threadIdx.x;
        int r   = idx >> 4;
        int c4  = (idx & 15) << 2;
        float4 v = *(const float4*)&xb[(size_t)(j0 + r) * DDIM + d0 + c4];
        ushort4 o;
        o.x = f2bf(v.x); o.y = f2bf(v.y); o.z = f2bf(v.z); o.w = f2bf(v.w);
        *(ushort4*)&tl[r][c4] = o;
    }
    __syncthreads();
    unsigned short* xtb = xT + (size_t)b * DDIM * NSEQ;
#pragma unroll
    for (int e = 0; e < 4; ++e) {
        int idx = e * 256 + threadIdx.x;
        int d   = idx >> 4;
        int jq  = (idx & 15) << 2;
        ushort4 o;
        o.x = tl[jq + 0][d]; o.y = tl[jq + 1][d];
        o.z = tl[jq + 2][d]; o.w = tl[jq + 3][d];
        *(ushort4*)&xtb[(size_t)(d0 + d) * NSEQ + j0 + jq] = o;
    }
}

// ---------------------------------------------------------------------------
// Kernel 2: build V-hat = full DIF-FFT (incl. r2) of exp(clamp(kernel)),
// digit-reversed order, pre-scaled by 1/8192.  ONE block, 512 threads.
// ---------------------------------------------------------------------------
__global__ __launch_bounds__(512) void build_V(const float* __restrict__ pos,
                                               const float* __restrict__ zero,
                                               const float* __restrict__ neg,
                                               cf* __restrict__ Vh) {
    __shared__ cf Z[PADI(FN)];
    int tid = threadIdx.x;
    float zv = zero[0];
#pragma unroll
    for (int q = 0; q < 16; ++q) {
        int t = q * 512 + tid;
        float v;
        if (t == 0 || t == NSEQ) v = zv;
        else if (t < NSEQ)       v = pos[t - 1];
        else                     v = neg[t - NSEQ - 1];
        v = fminf(fmaxf(v, -60.0f), 30.0f);
        Z[PADI(t)] = {__expf(v), 0.0f};
    }
    __syncthreads();
    r8_stage<-1, 512>(Z, 10, tid); __syncthreads();
    r8_stage<-1, 512>(Z, 7,  tid); __syncthreads();
    r8_stage<-1, 512>(Z, 4,  tid); __syncthreads();
    r8_stage<-1, 512>(Z, 1,  tid); __syncthreads();
    r2_stage<512>(Z, tid);         __syncthreads();
    const float sc = 1.0f / (float)FN;
#pragma unroll
    for (int q = 0; q < 16; ++q) {
        int i = q * 512 + tid;
        cf v = Z[PADI(i)];
        Vh[i] = {v.x * sc, v.y * sc};
    }
}

// ---------------------------------------------------------------------------
// Kernel 3: per column-pair FFT convolution, 512 threads.
// z = x_d + i*x_{d+1} -> 4 fwd r8 stages (first half-zero) -> fused
// [R2 diag(Vh) R2] pair-multiply -> 4 inv r8 stages -> write bf16 in place.
// ---------------------------------------------------------------------------
__global__ __launch_bounds__(512) void fft_conv(unsigned short* __restrict__ xT,
                                                const cf* __restrict__ Vh) {
    __shared__ cf Z[PADI(FN)];
    int tid = threadIdx.x;
    int blk = blockIdx.x;
    int b   = blk >> 8;
    int dp  = blk & 255;
    unsigned short* col0 = xT + ((size_t)(b * DDIM + 2 * dp)) * NSEQ;
    unsigned short* col1 = col0 + NSEQ;

    // load 4096 real pairs (upper half stays implicit-zero; r8_first knows)
#pragma unroll
    for (int q = 0; q < 2; ++q) {
        int i4 = (q * 512 + tid) * 4;
        ushort4 u0 = *(const ushort4*)&col0[i4];
        ushort4 u1 = *(const ushort4*)&col1[i4];
        Z[PADI(i4 + 0)] = {bf2f(u0.x), bf2f(u1.x)};
        Z[PADI(i4 + 1)] = {bf2f(u0.y), bf2f(u1.y)};
        Z[PADI(i4 + 2)] = {bf2f(u0.z), bf2f(u1.z)};
        Z[PADI(i4 + 3)] = {bf2f(u0.w), bf2f(u1.w)};
    }
    __syncthreads();

    r8_first<512>(Z, tid);         __syncthreads();
    r8_stage<-1, 512>(Z, 7, tid);  __syncthreads();
    r8_stage<-1, 512>(Z, 4, tid);  __syncthreads();
    r8_stage<-1, 512>(Z, 1, tid);  __syncthreads();

    // fused r2 + diag(Vh) + r2 on adjacent pairs (Vh pre-scaled by 1/8192)
    const float4* V4 = (const float4*)Vh;
#pragma unroll
    for (int q = 0; q < 8; ++q) {
        int p  = q * 512 + tid;
        float4 v = V4[p];
        cf V0 = {v.x, v.y}, V1 = {v.z, v.w};
        cf Vp = cadd(V0, V1), Vm = csub(V0, V1);
        int i0 = PADI(2 * p);
        cf z0 = Z[i0], z1 = Z[i0 + 1];
        Z[i0]     = cadd(cmul(Vp, z0), cmul(Vm, z1));
        Z[i0 + 1] = cadd(cmul(Vm, z0), cmul(Vp, z1));
    }
    __syncthreads();

    r8_stage<1, 512>(Z, 1, tid);   __syncthreads();
    r8_stage<1, 512>(Z, 4, tid);   __syncthreads();
    r8_stage<1, 512>(Z, 7, tid);   __syncthreads();
    r8_stage<1, 512>(Z, 10, tid);  __syncthreads();

#pragma unroll
    for (int q = 0; q < 2; ++q) {
        int i4 = (q * 512 + tid) * 4;
        cf v0 = Z[PADI(i4 + 0)], v1 = Z[PADI(i4 + 1)];
        cf v2 = Z[PADI(i4 + 2)], v3 = Z[PADI(i4 + 3)];
        ushort4 o0, o1;
        o0.x = f2bf(v0.x); o0.y = f2bf(v1.x); o0.z = f2bf(v2.x); o0.w = f2bf(v3.x);
        o1.x = f2bf(v0.y); o1.y = f2bf(v1.y); o1.z = f2bf(v2.y); o1.w = f2bf(v3.y);
        *(ushort4*)&col0[i4] = o0;
        *(ushort4*)&col1[i4] = o1;
    }
}

// ---------------------------------------------------------------------------
// Kernel 4: un-transpose  out[b][j][d] = f32(outT[b][d][j]).  grid (64,8,8).
// ---------------------------------------------------------------------------
__global__ void untranspose(const unsigned short* __restrict__ oT,
                            float* __restrict__ out) {
    __shared__ unsigned short tl[64][65];
    int j0 = blockIdx.x * 64, d0 = blockIdx.y * 64, b = blockIdx.z;
    const unsigned short* src = oT + (size_t)b * DDIM * NSEQ;
#pragma unroll
    for (int e = 0; e < 16; ++e) {
        int idx = e * 256 + threadIdx.x;
        int r = idx >> 6, c = idx & 63;
        tl[r][c] = src[(size_t)(d0 + r) * NSEQ + j0 + c];
    }
    __syncthreads();
    float* dst = out + ((size_t)b * NSEQ + j0) * DDIM + d0;
#pragma unroll
    for (int e = 0; e < 16; ++e) {
        int idx = e * 256 + threadIdx.x;
        int r = idx >> 6, c = idx & 63;
        dst[(size_t)r * DDIM + c] = bf2f(tl[c][r]);
    }
}

// ---------------------------------------------------------------------------
extern "C" void kernel_launch(void* const* d_in, const int* in_sizes, int n_in,
                              void* d_out, int out_size, void* d_ws, size_t ws_size,
                              hipStream_t stream) {
    const float* x    = (const float*)d_in[0];
    const float* pos  = (const float*)d_in[1];
    const float* zero = (const float*)d_in[2];
    const float* neg  = (const float*)d_in[3];
    float* out = (float*)d_out;

    unsigned short* xT = (unsigned short*)d_ws;                       // 32 MiB
    cf* Vh = (cf*)((char*)d_ws + (size_t)32 * 1024 * 1024);           // 64 KiB

    build_V<<<dim3(1), 512, 0, stream>>>(pos, zero, neg, Vh);
    transpose_x<<<dim3(4096), 256, 0, stream>>>(x, xT);
    fft_conv<<<dim3(NB * 256), 512, 0, stream>>>(xT, Vh);
    untranspose<<<dim3(64, 8, 8), 256, 0, stream>>>(xT, out);
}

// Round 13
// 123.933 us; speedup vs baseline: 1.6729x; 1.0457x over previous
//
#include <hip/hip_runtime.h>
#include <hip/hip_bf16.h>
#include <stdint.h>

#define NSEQ 4096
#define DDIM 512
#define NB   8
#define FN   8192          // FFT length = 2*NSEQ

#define PADI(i) ((i) + ((i) >> 5))

struct __align__(8) cf { float x, y; };

__device__ __forceinline__ cf cadd(cf a, cf b) { return {a.x + b.x, a.y + b.y}; }
__device__ __forceinline__ cf csub(cf a, cf b) { return {a.x - b.x, a.y - b.y}; }
__device__ __forceinline__ cf cmul(cf a, cf b) {
    return {a.x * b.x - a.y * b.y, a.x * b.y + a.y * b.x};
}
template<int DIR> __device__ __forceinline__ cf crot(cf z) {  // *(-i) fwd, *(+i) inv
    return DIR < 0 ? cf{z.y, -z.x} : cf{-z.y, z.x};
}

__device__ __forceinline__ unsigned short f2bf(float f) {
    union { float f; unsigned int u; } v;
    v.f = f;
    unsigned int u = v.u;
    u += 0x7FFFu + ((u >> 16) & 1u);   // RNE
    return (unsigned short)(u >> 16);
}
__device__ __forceinline__ float bf2f(unsigned short u) {
    union { unsigned int i; float f; } v;
    v.i = (unsigned int)u << 16;
    return v.f;
}

// ---------------------------------------------------------------------------
// 8-point DFT pieces
// ---------------------------------------------------------------------------
template<int DIR>
__device__ __forceinline__ void fft4(cf& b0, cf& b1, cf& b2, cf& b3) {
    cf s0 = cadd(b0, b2), s1 = csub(b0, b2);
    cf s2 = cadd(b1, b3), s3 = crot<DIR>(csub(b1, b3));
    b0 = cadd(s0, s2); b1 = cadd(s1, s3);
    b2 = csub(s0, s2); b3 = csub(s1, s3);
}

template<int DIR>
__device__ __forceinline__ void dft8(cf a[8]) {
    cf e0 = a[0], e1 = a[2], e2 = a[4], e3 = a[6];
    cf o0 = a[1], o1 = a[3], o2 = a[5], o3 = a[7];
    fft4<DIR>(e0, e1, e2, e3);
    fft4<DIR>(o0, o1, o2, o3);
    const float c = 0.70710678118654752f;
    cf w1 = (DIR < 0) ? cf{c, -c} : cf{c, c};
    cf w3 = (DIR < 0) ? cf{-c, -c} : cf{-c, c};
    o1 = cmul(o1, w1);
    o2 = crot<DIR>(o2);
    o3 = cmul(o3, w3);
    a[0] = cadd(e0, o0); a[1] = cadd(e1, o1); a[2] = cadd(e2, o2); a[3] = cadd(e3, o3);
    a[4] = csub(e0, o0); a[5] = csub(e1, o1); a[6] = csub(e2, o2); a[7] = csub(e3, o3);
}

// DFT8 with a[4..7] == 0 (zero-padded upper half), inputs a0..a3
template<int DIR>
__device__ __forceinline__ void dft8_half(cf a0, cf a1, cf a2, cf a3, cf a[8]) {
    cf r2 = crot<DIR>(a2), r3 = crot<DIR>(a3);
    cf e0 = cadd(a0, a2), e1 = cadd(a0, r2), e2 = csub(a0, a2), e3 = csub(a0, r2);
    cf o0 = cadd(a1, a3), o1 = cadd(a1, r3), o2 = csub(a1, a3), o3 = csub(a1, r3);
    const float c = 0.70710678118654752f;
    cf w1 = (DIR < 0) ? cf{c, -c} : cf{c, c};
    cf w3 = (DIR < 0) ? cf{-c, -c} : cf{-c, c};
    o1 = cmul(o1, w1);
    o2 = crot<DIR>(o2);
    o3 = cmul(o3, w3);
    a[0] = cadd(e0, o0); a[1] = cadd(e1, o1); a[2] = cadd(e2, o2); a[3] = cadd(e3, o3);
    a[4] = csub(e0, o0); a[5] = csub(e1, o1); a[6] = csub(e2, o2); a[7] = csub(e3, o3);
}

// depth-3 twiddle powers w[k] = w1^k, k=1..7
__device__ __forceinline__ void twpow(cf w1, cf w[8]) {
    w[1] = w1;
    w[2] = cmul(w1, w1);
    w[3] = cmul(w[2], w1);
    w[4] = cmul(w[2], w[2]);
    w[5] = cmul(w[4], w1);
    w[6] = cmul(w[4], w[2]);
    w[7] = cmul(w[4], w[3]);
}

// ---------------------------------------------------------------------------
// One radix-8 stage over LDS, in place.  1024 butterflies, NTHR threads.
// ---------------------------------------------------------------------------
template<int DIR, int NTHR>
__device__ __forceinline__ void r8_stage(cf* Z, int lm, int tid) {
    const int m = 1 << lm;
    const float ang0 = ((DIR < 0) ? -6.2831853071795865f : 6.2831853071795865f)
                       / (float)(m * 8);
#pragma unroll
    for (int q = 0; q < 1024 / NTHR; ++q) {
        int beta = q * NTHR + tid;
        int j = beta & (m - 1);
        int g = beta >> lm;
        int base = (g << (lm + 3)) + j;
        cf a[8];
#pragma unroll
        for (int r = 0; r < 8; ++r) a[r] = Z[PADI(base + (r << lm))];
        float sn, cs;
        __sincosf(ang0 * (float)j, &sn, &cs);
        cf w[8];
        twpow({cs, sn}, w);
        if (DIR > 0) {
#pragma unroll
            for (int k = 1; k < 8; ++k) a[k] = cmul(a[k], w[k]);
        }
        dft8<DIR>(a);
        if (DIR < 0) {
#pragma unroll
            for (int k = 1; k < 8; ++k) a[k] = cmul(a[k], w[k]);
        }
#pragma unroll
        for (int r = 0; r < 8; ++r) Z[PADI(base + (r << lm))] = a[r];
    }
}

// radix-2 stage on adjacent pairs (used only in build_V's full chain)
template<int NTHR>
__device__ __forceinline__ void r2_stage(cf* Z, int tid) {
#pragma unroll
    for (int q = 0; q < 4096 / NTHR; ++q) {
        int beta = q * NTHR + tid;
        int i0 = PADI(2 * beta), i1 = i0 + 1;
        cf a = Z[i0], b = Z[i1];
        Z[i0] = cadd(a, b);
        Z[i1] = csub(a, b);
    }
}

// ---------------------------------------------------------------------------
// Kernel 1: transpose+convert  xT[b][d][j] = bf16(x[b][j][d]).  4096 blocks.
// ---------------------------------------------------------------------------
__global__ void transpose_x(const float* __restrict__ x,
                            unsigned short* __restrict__ xT) {
    __shared__ unsigned short tl[64][72];
    int t   = blockIdx.x;
    int b   = t >> 9;
    int rem = t & 511;
    int j0  = (rem >> 3) << 6;
    int d0  = (rem & 7) << 6;
    const float* xb = x + (size_t)b * NSEQ * DDIM;
#pragma unroll
    for (int e = 0; e < 4; ++e) {
        int idx = e * 256 + threadIdx.x;
        int r   = idx >> 4;
        int c4  = (idx & 15) << 2;
        float4 v = *(const float4*)&xb[(size_t)(j0 + r) * DDIM + d0 + c4];
        ushort4 o;
        o.x = f2bf(v.x); o.y = f2bf(v.y); o.z = f2bf(v.z); o.w = f2bf(v.w);
        *(ushort4*)&tl[r][c4] = o;
    }
    __syncthreads();
    unsigned short* xtb = xT + (size_t)b * DDIM * NSEQ;
#pragma unroll
    for (int e = 0; e < 4; ++e) {
        int idx = e * 256 + threadIdx.x;
        int d   = idx >> 4;
        int jq  = (idx & 15) << 2;
        ushort4 o;
        o.x = tl[jq + 0][d]; o.y = tl[jq + 1][d];
        o.z = tl[jq + 2][d]; o.w = tl[jq + 3][d];
        *(ushort4*)&xtb[(size_t)(d0 + d) * NSEQ + j0 + jq] = o;
    }
}

// ---------------------------------------------------------------------------
// Kernel 2: build V-hat = full DIF-FFT (incl. r2) of exp(clamp(kernel)),
// digit-reversed order, pre-scaled by 1/8192.  ONE block, 512 threads.
// ---------------------------------------------------------------------------
__global__ __launch_bounds__(512) void build_V(const float* __restrict__ pos,
                                               const float* __restrict__ zero,
                                               const float* __restrict__ neg,
                                               cf* __restrict__ Vh) {
    __shared__ cf Z[PADI(FN)];
    int tid = threadIdx.x;
    float zv = zero[0];
#pragma unroll
    for (int q = 0; q < 16; ++q) {
        int t = q * 512 + tid;
        float v;
        if (t == 0 || t == NSEQ) v = zv;
        else if (t < NSEQ)       v = pos[t - 1];
        else                     v = neg[t - NSEQ - 1];
        v = fminf(fmaxf(v, -60.0f), 30.0f);
        Z[PADI(t)] = {__expf(v), 0.0f};
    }
    __syncthreads();
    r8_stage<-1, 512>(Z, 10, tid); __syncthreads();
    r8_stage<-1, 512>(Z, 7,  tid); __syncthreads();
    r8_stage<-1, 512>(Z, 4,  tid); __syncthreads();
    r8_stage<-1, 512>(Z, 1,  tid); __syncthreads();
    r2_stage<512>(Z, tid);         __syncthreads();
    const float sc = 1.0f / (float)FN;
#pragma unroll
    for (int q = 0; q < 16; ++q) {
        int i = q * 512 + tid;
        cf v = Z[PADI(i)];
        Vh[i] = {v.x * sc, v.y * sc};
    }
}

// ---------------------------------------------------------------------------
// Kernel 3: per column-pair FFT convolution, 1024 threads, 2 blocks/CU.
// First fwd stage fused with global load (regs, half-zero DFT8); last inv
// stage fused with global store (only outputs < 4096 written).
// ---------------------------------------------------------------------------
__global__ __launch_bounds__(1024, 8) void fft_conv(unsigned short* __restrict__ xT,
                                                    const cf* __restrict__ Vh) {
    __shared__ cf Z[PADI(FN)];
    int tid = threadIdx.x;
    int blk = blockIdx.x;
    int b   = blk >> 8;
    int dp  = blk & 255;
    unsigned short* col0 = xT + ((size_t)(b * DDIM + 2 * dp)) * NSEQ;
    unsigned short* col1 = col0 + NSEQ;

    // ---- fused load + first forward stage (lm=10, half-zero) ----
    {
        int j = tid;
        cf a0 = {bf2f(col0[j]),        bf2f(col1[j])};
        cf a1 = {bf2f(col0[j + 1024]), bf2f(col1[j + 1024])};
        cf a2 = {bf2f(col0[j + 2048]), bf2f(col1[j + 2048])};
        cf a3 = {bf2f(col0[j + 3072]), bf2f(col1[j + 3072])};
        cf a[8];
        dft8_half<-1>(a0, a1, a2, a3, a);
        const float ang0 = -6.2831853071795865f / 8192.0f;
        float sn, cs;
        __sincosf(ang0 * (float)j, &sn, &cs);
        cf w[8];
        twpow({cs, sn}, w);
#pragma unroll
        for (int k = 1; k < 8; ++k) a[k] = cmul(a[k], w[k]);
#pragma unroll
        for (int r = 0; r < 8; ++r) Z[PADI(j + (r << 10))] = a[r];
    }
    __syncthreads();

    r8_stage<-1, 1024>(Z, 7, tid);  __syncthreads();
    r8_stage<-1, 1024>(Z, 4, tid);  __syncthreads();
    r8_stage<-1, 1024>(Z, 1, tid);  __syncthreads();

    // ---- fused r2 + diag(Vh) + r2 on adjacent pairs (Vh pre-scaled) ----
    const float4* V4 = (const float4*)Vh;
#pragma unroll
    for (int q = 0; q < 4; ++q) {
        int p  = q * 1024 + tid;
        float4 v = V4[p];
        cf V0 = {v.x, v.y}, V1 = {v.z, v.w};
        cf Vp = cadd(V0, V1), Vm = csub(V0, V1);
        int i0 = PADI(2 * p);
        cf z0 = Z[i0], z1 = Z[i0 + 1];
        Z[i0]     = cadd(cmul(Vp, z0), cmul(Vm, z1));
        Z[i0 + 1] = cadd(cmul(Vm, z0), cmul(Vp, z1));
    }
    __syncthreads();

    r8_stage<1, 1024>(Z, 1, tid);   __syncthreads();
    r8_stage<1, 1024>(Z, 4, tid);   __syncthreads();
    r8_stage<1, 1024>(Z, 7, tid);   __syncthreads();

    // ---- fused last inverse stage (lm=10) + store (only idx < 4096) ----
    {
        int j = tid;
        cf a[8];
#pragma unroll
        for (int r = 0; r < 8; ++r) a[r] = Z[PADI(j + (r << 10))];
        const float ang0 = 6.2831853071795865f / 8192.0f;
        float sn, cs;
        __sincosf(ang0 * (float)j, &sn, &cs);
        cf w[8];
        twpow({cs, sn}, w);
#pragma unroll
        for (int k = 1; k < 8; ++k) a[k] = cmul(a[k], w[k]);
        dft8<1>(a);
#pragma unroll
        for (int r = 0; r < 4; ++r) {
            col0[j + (r << 10)] = f2bf(a[r].x);
            col1[j + (r << 10)] = f2bf(a[r].y);
        }
    }
}

// ---------------------------------------------------------------------------
// Kernel 4: un-transpose  out[b][j][d] = f32(outT[b][d][j]).  grid (64,8,8).
// ---------------------------------------------------------------------------
__global__ void untranspose(const unsigned short* __restrict__ oT,
                            float* __restrict__ out) {
    __shared__ unsigned short tl[64][65];
    int j0 = blockIdx.x * 64, d0 = blockIdx.y * 64, b = blockIdx.z;
    const unsigned short* src = oT + (size_t)b * DDIM * NSEQ;
#pragma unroll
    for (int e = 0; e < 16; ++e) {
        int idx = e * 256 + threadIdx.x;
        int r = idx >> 6, c = idx & 63;
        tl[r][c] = src[(size_t)(d0 + r) * NSEQ + j0 + c];
    }
    __syncthreads();
    float* dst = out + ((size_t)b * NSEQ + j0) * DDIM + d0;
#pragma unroll
    for (int e = 0; e < 16; ++e) {
        int idx = e * 256 + threadIdx.x;
        int r = idx >> 6, c = idx & 63;
        dst[(size_t)r * DDIM + c] = bf2f(tl[c][r]);
    }
}

// ---------------------------------------------------------------------------
extern "C" void kernel_launch(void* const* d_in, const int* in_sizes, int n_in,
                              void* d_out, int out_size, void* d_ws, size_t ws_size,
                              hipStream_t stream) {
    const float* x    = (const float*)d_in[0];
    const float* pos  = (const float*)d_in[1];
    const float* zero = (const float*)d_in[2];
    const float* neg  = (const float*)d_in[3];
    float* out = (float*)d_out;

    unsigned short* xT = (unsigned short*)d_ws;                       // 32 MiB
    cf* Vh = (cf*)((char*)d_ws + (size_t)32 * 1024 * 1024);           // 64 KiB

    build_V<<<dim3(1), 512, 0, stream>>>(pos, zero, neg, Vh);
    transpose_x<<<dim3(4096), 256, 0, stream>>>(x, xT);
    fft_conv<<<dim3(NB * 256), 1024, 0, stream>>>(xT, Vh);
    untranspose<<<dim3(64, 8, 8), 256, 0, stream>>>(xT, out);
}